// Round 3
// baseline (571.803 us; speedup 1.0000x reference)
//
#include <hip/hip_runtime.h>
#include <hip/hip_cooperative_groups.h>
#include <math.h>

namespace cg = cooperative_groups;

#define TV 3200          // T*V = 128*25
#define NTV 204800       // N*T*V
#define NBC 400          // cooperative grid: 400 blocks x 256 thr x 2 positions
#define NBF 800          // fallback grid
constexpr float EPSF = 1e-5f;

struct Params {
  const float *x, *Wv, *bv, *Ww, *bw, *g_bn, *b_bn, *Wr, *br, *g_r, *b_r, *Wo, *bo, *g_o, *b_o;
  float *v0, *s, *pr, *patt, *ph, *out;
};

// wave shuffle -> LDS -> per-block partial; trailing sync so lds can be reused
template<int NS>
__device__ inline void partials(const float (&vals)[NS], float* lds, float* out, int ncols){
  int lane = threadIdx.x & 63;
  int wid  = threadIdx.x >> 6;
  #pragma unroll
  for (int j = 0; j < NS; ++j){
    float v = vals[j];
    #pragma unroll
    for (int o = 32; o > 0; o >>= 1) v += __shfl_down(v, o);
    if (lane == 0) lds[j*4 + wid] = v;
  }
  __syncthreads();
  if ((int)threadIdx.x < NS){
    out[threadIdx.x*ncols + blockIdx.x] =
      lds[threadIdx.x*4+0] + lds[threadIdx.x*4+1] + lds[threadIdx.x*4+2] + lds[threadIdx.x*4+3];
  }
  __syncthreads();
}

// ====================== cooperative mega-kernel ======================
// smem map over time (floats, total 1536):
//  A: [0..1023] Wv|Wr, then partials area [0..63]
//  B: Ww at [1280..1404], bw at [1408..1432]; partials [0..63]
//  C: chunk sums [0..511]; coef at [512..543]
//  D: partials [0..175]
//  E: chunks [0..175]; stats44 [1200..1243]; doubles [1248..1391]; fold [0..1023]; bfold [1024..1151]
//  F: fold/bfold read from smem
__global__ __launch_bounds__(256, 2) void mega(Params P){
  cg::grid_group grid = cg::this_grid();
  __shared__ __align__(16) float smem[1536];
  const int tid = threadIdx.x;
  int p[2], nn[2], tv[2], tt_[2], vv[2];
  p[0] = blockIdx.x*512 + tid;
  p[1] = p[0] + 256;
  #pragma unroll
  for (int q = 0; q < 2; ++q){
    nn[q] = p[q] / TV; tv[q] = p[q] - nn[q]*TV;
    tt_[q] = tv[q] / 25; vv[q] = tv[q] - tt_[q]*25;
  }

  // ---------- Phase A: v0, s, r0(regs) + r0 stats ----------
  for (int i = tid; i < 512; i += 256){ smem[i] = P.Wv[i]; smem[512+i] = P.Wr[i]; }
  __syncthreads();
  float av[2][8] = {}, ar[2][8] = {}, ss[2] = {0.f, 0.f};
  const float* xp[2];
  #pragma unroll
  for (int q = 0; q < 2; ++q) xp[q] = P.x + (size_t)nn[q]*64*TV + tv[q];
  for (int c = 0; c < 64; ++c){
    #pragma unroll
    for (int q = 0; q < 2; ++q){
      float xv = xp[q][(size_t)c*TV];
      ss[q] += xv;
      #pragma unroll
      for (int r = 0; r < 8; ++r){
        av[q][r] = fmaf(smem[r*64+c], xv, av[q][r]);
        ar[q][r] = fmaf(smem[512+r*64+c], xv, ar[q][r]);
      }
    }
  }
  float r0r[2][8];
  {
    float vals[16];
    #pragma unroll
    for (int q = 0; q < 2; ++q){
      P.s[p[q]] = ss[q] * 0.015625f;
      float* v0p = P.v0 + (size_t)nn[q]*8*TV + tv[q];
      #pragma unroll
      for (int r = 0; r < 8; ++r){
        v0p[(size_t)r*TV] = av[q][r] + P.bv[r];
        r0r[q][r] = ar[q][r] + P.br[r];
      }
    }
    #pragma unroll
    for (int r = 0; r < 8; ++r){
      vals[r]   = r0r[0][r] + r0r[1][r];
      vals[8+r] = r0r[0][r]*r0r[0][r] + r0r[1][r]*r0r[1][r];
    }
    __syncthreads();
    partials<16>(vals, smem, P.pr, NBC);
  }
  __threadfence();
  grid.sync();
  __threadfence();

  // ---------- Phase B: W2 inline + att(regs) + att stats ----------
  if (tid < 125) smem[1280+tid] = P.Ww[tid];
  if (tid < 25)  smem[1408+tid] = P.bw[tid];
  __syncthreads();
  float attr[2][8] = {};
  #pragma unroll
  for (int q = 0; q < 2; ++q){
    float m[5];
    #pragma unroll
    for (int k = 0; k < 5; ++k){
      int tt = tt_[q] + k - 2;
      m[k] = (tt >= 0 && tt < 128) ? P.s[nn[q]*TV + tt*25 + vv[q]] : 0.f;
    }
    const float* v0n = P.v0 + (size_t)nn[q]*8*TV;
    #pragma unroll
    for (int u = 0; u < 5; ++u){
      float w2u = 0.f;
      #pragma unroll
      for (int w = 0; w < 5; ++w){
        int o = w*5 + u;
        float acc = smem[1408+o];
        #pragma unroll
        for (int k = 0; k < 5; ++k) acc = fmaf(smem[1280+o*5+k], m[k], acc);
        w2u += tanhf(acc);
      }
      int tt = tt_[q] + u - 2;
      if (tt >= 0 && tt < 128){
        const float* vp = v0n + tt*25 + vv[q];
        #pragma unroll
        for (int r = 0; r < 8; ++r) attr[q][r] = fmaf(w2u, vp[(size_t)r*TV], attr[q][r]);
      }
    }
  }
  {
    float vals[16];
    #pragma unroll
    for (int r = 0; r < 8; ++r){
      vals[r]   = attr[0][r] + attr[1][r];
      vals[8+r] = attr[0][r]*attr[0][r] + attr[1][r]*attr[1][r];
    }
    __syncthreads();
    partials<16>(vals, smem, P.patt, NBC);
  }
  __threadfence();
  grid.sync();
  __threadfence();

  // ---------- Phase C: EVERY block reduces BN coefs into smem[512..543] ----------
  {
    int ch = tid >> 4, chunk = tid & 15;       // 16 channels x 16 chunks of 25
    const float* base = (ch >= 8) ? P.patt : P.pr;
    int r = ch & 7;
    const float* ps = base + r*NBC + chunk*25;
    const float* pq = base + (8+r)*NBC + chunk*25;
    float s1 = 0.f, s2 = 0.f;
    for (int i = 0; i < 25; ++i){ s1 += ps[i]; s2 += pq[i]; }
    smem[tid] = s1; smem[256+tid] = s2;
    __syncthreads();
    if (tid < 16){
      float sum = 0.f, sq = 0.f;
      #pragma unroll
      for (int i = 0; i < 16; ++i){ sum += smem[tid*16+i]; sq += smem[256+tid*16+i]; }
      float mu  = sum / (float)NTV;
      float var = sq / (float)NTV - mu*mu;
      bool isatt = (tid >= 8); int rr = tid & 7;
      float g  = isatt ? P.g_bn[rr] : P.g_r[rr];
      float bb = isatt ? P.b_bn[rr] : P.b_r[rr];
      float a  = g * rsqrtf(var + EPSF);
      int b0 = isatt ? 512 : 528;
      smem[b0+rr] = a; smem[b0+8+rr] = bb - a*mu;
    }
    __syncthreads();
  }

  // ---------- Phase D: h(regs) + 44 moment partials ----------
  float hv[2][8];
  #pragma unroll
  for (int q = 0; q < 2; ++q)
    #pragma unroll
    for (int r = 0; r < 8; ++r){
      float z = smem[512+r]*attr[q][r] + smem[520+r] + smem[528+r]*r0r[q][r] + smem[536+r];
      hv[q][r] = (z >= 0.f) ? z : 0.1f*z;
    }
  {
    float vals[44];
    #pragma unroll
    for (int r = 0; r < 8; ++r) vals[r] = hv[0][r] + hv[1][r];
    int cnt = 8;
    #pragma unroll
    for (int r = 0; r < 8; ++r)
      #pragma unroll
      for (int r2 = r; r2 < 8; ++r2){
        vals[cnt++] = hv[0][r]*hv[0][r2] + hv[1][r]*hv[1][r2];
      }
    __syncthreads();
    partials<44>(vals, smem, P.ph, NBC);
  }
  __threadfence();
  grid.sync();
  __threadfence();

  // ---------- Phase E: EVERY block reduces 44 stats + analytic fold into smem ----------
  {
    if (tid < 176){
      int j = tid >> 2, qk = tid & 3;
      const float* row = P.ph + j*NBC + qk*100;
      float acc = 0.f;
      for (int i = 0; i < 100; ++i) acc += row[i];
      smem[tid] = acc;
    }
    __syncthreads();
    if (tid < 44)
      smem[1200+tid] = smem[4*tid]+smem[4*tid+1]+smem[4*tid+2]+smem[4*tid+3];
    __syncthreads();
    double* muh = (double*)(smem + 1248);   // 8 doubles
    double* exx = (double*)(smem + 1264);   // 64 doubles
    if (tid < 8) muh[tid] = (double)smem[1200+tid] / (double)NTV;
    if (tid == 0){
      int cnt = 8;
      for (int r = 0; r < 8; ++r)
        for (int r2 = r; r2 < 8; ++r2){
          double e = (double)smem[1200+cnt] / (double)NTV; cnt++;
          exx[r*8+r2] = e; exx[r2*8+r] = e;
        }
    }
    __syncthreads();
    if (tid < 128){
      double w[8];
      #pragma unroll
      for (int r = 0; r < 8; ++r) w[r] = (double)P.Wo[tid*8+r];
      double bob = (double)P.bo[tid];
      double mu = bob;
      for (int r = 0; r < 8; ++r) mu += w[r]*muh[r];
      double t2 = 0.0;
      for (int r = 0; r < 8; ++r)
        for (int r2 = 0; r2 < 8; ++r2) t2 += w[r]*w[r2]*exx[r*8+r2];
      double ey2 = t2 + 2.0*bob*(mu - bob) + bob*bob;
      double var = ey2 - mu*mu;
      double a = (double)P.g_o[tid] / sqrt(var + (double)EPSF);
      #pragma unroll
      for (int r = 0; r < 8; ++r) smem[tid*8+r] = (float)(a * w[r]);   // fold
      smem[1024+tid] = (float)(a * (bob - mu) + (double)P.b_o[tid]);   // bfold
    }
    __syncthreads();
  }

  // ---------- Phase F: out = fold . h + bfold ----------
  #pragma unroll
  for (int q = 0; q < 2; ++q){
    float* op = P.out + (size_t)nn[q]*128*TV + tv[q];
    #pragma unroll 4
    for (int o = 0; o < 128; ++o){
      float y = smem[1024+o];
      #pragma unroll
      for (int r = 0; r < 8; ++r) y = fmaf(smem[o*8+r], hv[q][r], y);
      op[(size_t)o*TV] = y;
    }
  }
}

// ====================== fallback chain (verified Round 1) ======================
__global__ __launch_bounds__(256) void k_proj(const float* __restrict__ x,
    const float* __restrict__ Wv, const float* __restrict__ bv,
    const float* __restrict__ Wr, const float* __restrict__ br,
    float* __restrict__ v0, float* __restrict__ r0, float* __restrict__ s,
    float* __restrict__ pr){
  __shared__ float sWv[512], sWr[512], lds[16*4];
  int tid = threadIdx.x;
  for (int i = tid; i < 512; i += 256){ sWv[i] = Wv[i]; sWr[i] = Wr[i]; }
  __syncthreads();
  int p = blockIdx.x*256 + tid;
  int n = p / TV, tv = p - n*TV;
  const float* xp = x + (size_t)n*64*TV + tv;
  float av[8] = {}, ar[8] = {};
  float ssum = 0.f;
  for (int c = 0; c < 64; ++c){
    float xv = xp[(size_t)c*TV];
    ssum += xv;
    #pragma unroll
    for (int r = 0; r < 8; ++r){
      av[r] = fmaf(sWv[r*64+c], xv, av[r]);
      ar[r] = fmaf(sWr[r*64+c], xv, ar[r]);
    }
  }
  s[p] = ssum * 0.015625f;
  float* v0p = v0 + (size_t)n*8*TV + tv;
  float* r0p = r0 + (size_t)n*8*TV + tv;
  float vals[16];
  #pragma unroll
  for (int r = 0; r < 8; ++r){
    v0p[(size_t)r*TV] = av[r] + bv[r];
    float rr = ar[r] + br[r];
    r0p[(size_t)r*TV] = rr;
    vals[r] = rr; vals[8+r] = rr*rr;
  }
  partials<16>(vals, lds, pr, NBF);
}

__global__ __launch_bounds__(256) void k_att(const float* __restrict__ s,
    const float* __restrict__ Ww, const float* __restrict__ bw,
    const float* __restrict__ v0, float* __restrict__ att, float* __restrict__ patt){
  __shared__ float sWw[125], sbw[25], lds[16*4];
  int tid = threadIdx.x;
  if (tid < 125) sWw[tid] = Ww[tid];
  if (tid < 25)  sbw[tid] = bw[tid];
  __syncthreads();
  int p = blockIdx.x*256 + tid;
  int n = p / TV, tv = p - n*TV;
  int t = tv / 25, v = tv - t*25;
  float m[5];
  #pragma unroll
  for (int k = 0; k < 5; ++k){
    int tt = t + k - 2;
    m[k] = (tt >= 0 && tt < 128) ? s[n*TV + tt*25 + v] : 0.f;
  }
  float a[8] = {};
  const float* v0n = v0 + (size_t)n*8*TV;
  #pragma unroll
  for (int u = 0; u < 5; ++u){
    float w2u = 0.f;
    #pragma unroll
    for (int w = 0; w < 5; ++w){
      int o = w*5 + u;
      float acc = sbw[o];
      #pragma unroll
      for (int k = 0; k < 5; ++k) acc = fmaf(sWw[o*5+k], m[k], acc);
      w2u += tanhf(acc);
    }
    int tt = t + u - 2;
    if (tt >= 0 && tt < 128){
      const float* vp = v0n + tt*25 + v;
      #pragma unroll
      for (int r = 0; r < 8; ++r) a[r] = fmaf(w2u, vp[(size_t)r*TV], a[r]);
    }
  }
  float* ap = att + (size_t)n*8*TV + tv;
  float vals[16];
  #pragma unroll
  for (int r = 0; r < 8; ++r){
    ap[(size_t)r*TV] = a[r];
    vals[r] = a[r]; vals[8+r] = a[r]*a[r];
  }
  partials<16>(vals, lds, patt, NBF);
}

__global__ __launch_bounds__(256) void k_bncoef(const float* __restrict__ pr,
    const float* __restrict__ patt,
    const float* __restrict__ g_bn, const float* __restrict__ b_bn,
    const float* __restrict__ g_r, const float* __restrict__ b_r,
    float* __restrict__ coef){
  __shared__ float lds[8];
  int b = blockIdx.x;
  bool isatt = (b >= 8);
  int r = isatt ? b - 8 : b;
  const float* ps = (isatt ? patt : pr) + r*NBF;
  const float* pq = (isatt ? patt : pr) + (8+r)*NBF;
  float s1 = 0.f, s2 = 0.f;
  for (int i = threadIdx.x; i < NBF; i += 256){ s1 += ps[i]; s2 += pq[i]; }
  int lane = threadIdx.x & 63, wid = threadIdx.x >> 6;
  #pragma unroll
  for (int o = 32; o > 0; o >>= 1){ s1 += __shfl_down(s1, o); s2 += __shfl_down(s2, o); }
  if (lane == 0){ lds[wid] = s1; lds[4+wid] = s2; }
  __syncthreads();
  if (threadIdx.x == 0){
    float sum = lds[0]+lds[1]+lds[2]+lds[3];
    float sq  = lds[4]+lds[5]+lds[6]+lds[7];
    float mu  = sum / (float)NTV;
    float var = sq / (float)NTV - mu*mu;
    float g  = isatt ? g_bn[r] : g_r[r];
    float bb = isatt ? b_bn[r] : b_r[r];
    float a = g * rsqrtf(var + EPSF);
    int base = isatt ? 0 : 16;
    coef[base + r] = a;
    coef[base + 8 + r] = bb - a*mu;
  }
}

__global__ __launch_bounds__(256) void k_h(const float* __restrict__ att,
    const float* __restrict__ r0, const float* __restrict__ coef,
    float* __restrict__ h, float* __restrict__ ph){
  __shared__ float lds[44*4];
  __shared__ float sc[32];
  int tid = threadIdx.x;
  if (tid < 32) sc[tid] = coef[tid];
  __syncthreads();
  int p = blockIdx.x*256 + tid;
  int n = p / TV, tv = p - n*TV;
  const float* ap = att + (size_t)n*8*TV + tv;
  const float* rp = r0  + (size_t)n*8*TV + tv;
  float* hp = h + (size_t)n*8*TV + tv;
  float hvv[8];
  #pragma unroll
  for (int r = 0; r < 8; ++r){
    float z = sc[r]*ap[(size_t)r*TV] + sc[8+r] + sc[16+r]*rp[(size_t)r*TV] + sc[24+r];
    hvv[r] = (z >= 0.f) ? z : 0.1f*z;
    hp[(size_t)r*TV] = hvv[r];
  }
  float vals[44];
  #pragma unroll
  for (int r = 0; r < 8; ++r) vals[r] = hvv[r];
  int cnt = 8;
  #pragma unroll
  for (int r = 0; r < 8; ++r)
    #pragma unroll
    for (int r2 = r; r2 < 8; ++r2) vals[cnt++] = hvv[r]*hvv[r2];
  partials<44>(vals, lds, ph, NBF);
}

__global__ __launch_bounds__(256) void k_hred(const float* __restrict__ ph,
    float* __restrict__ hstat){
  __shared__ float lds[4];
  int j = blockIdx.x;
  float s1 = 0.f;
  for (int i = threadIdx.x; i < NBF; i += 256) s1 += ph[j*NBF + i];
  int lane = threadIdx.x & 63, wid = threadIdx.x >> 6;
  #pragma unroll
  for (int o = 32; o > 0; o >>= 1) s1 += __shfl_down(s1, o);
  if (lane == 0) lds[wid] = s1;
  __syncthreads();
  if (threadIdx.x == 0) hstat[j] = lds[0]+lds[1]+lds[2]+lds[3];
}

__global__ __launch_bounds__(128) void k_fold(const float* __restrict__ hstat,
    const float* __restrict__ Wo, const float* __restrict__ bo,
    const float* __restrict__ g_o, const float* __restrict__ b_o,
    float* __restrict__ fold, float* __restrict__ bfold){
  __shared__ double muh[8];
  __shared__ double exx[8][8];
  int o = threadIdx.x;
  if (o < 8) muh[o] = (double)hstat[o] / (double)NTV;
  if (o == 0){
    int cnt = 8;
    for (int r = 0; r < 8; ++r)
      for (int r2 = r; r2 < 8; ++r2){
        double e = (double)hstat[cnt++] / (double)NTV;
        exx[r][r2] = e; exx[r2][r] = e;
      }
  }
  __syncthreads();
  double w[8];
  for (int r = 0; r < 8; ++r) w[r] = (double)Wo[o*8+r];
  double bob = (double)bo[o];
  double mu = bob;
  for (int r = 0; r < 8; ++r) mu += w[r]*muh[r];
  double t = 0.0;
  for (int r = 0; r < 8; ++r)
    for (int r2 = 0; r2 < 8; ++r2) t += w[r]*w[r2]*exx[r][r2];
  double ey2 = t + 2.0*bob*(mu - bob) + bob*bob;
  double var = ey2 - mu*mu;
  double a = (double)g_o[o] / sqrt(var + (double)EPSF);
  for (int r = 0; r < 8; ++r) fold[o*8+r] = (float)(a * w[r]);
  bfold[o] = (float)(a * (bob - mu) + (double)b_o[o]);
}

__global__ __launch_bounds__(256) void k_out(const float* __restrict__ h,
    const float* __restrict__ fold, const float* __restrict__ bfold,
    float* __restrict__ out){
  __shared__ float sW[1024], sB[128];
  int tid = threadIdx.x;
  for (int i = tid; i < 1024; i += 256) sW[i] = fold[i];
  if (tid < 128) sB[tid] = bfold[tid];
  __syncthreads();
  int p = blockIdx.x*256 + tid;
  int n = p / TV, tv = p - n*TV;
  const float* hp = h + (size_t)n*8*TV + tv;
  float hvv[8];
  #pragma unroll
  for (int r = 0; r < 8; ++r) hvv[r] = hp[(size_t)r*TV];
  float* op = out + (size_t)n*128*TV + tv;
  #pragma unroll 4
  for (int o = 0; o < 128; ++o){
    float y = sB[o];
    #pragma unroll
    for (int r = 0; r < 8; ++r) y = fmaf(sW[o*8+r], hvv[r], y);
    op[(size_t)o*TV] = y;
  }
}

extern "C" void kernel_launch(void* const* d_in, const int* in_sizes, int n_in,
                              void* d_out, int out_size, void* d_ws, size_t ws_size,
                              hipStream_t stream){
  float* ws = (float*)d_ws;
  size_t off = 0;
  Params P;
  P.x    = (const float*)d_in[0];
  P.Wv   = (const float*)d_in[1];
  P.bv   = (const float*)d_in[2];
  P.Ww   = (const float*)d_in[3];
  P.bw   = (const float*)d_in[4];
  P.g_bn = (const float*)d_in[5];
  P.b_bn = (const float*)d_in[6];
  P.Wr   = (const float*)d_in[7];
  P.br   = (const float*)d_in[8];
  P.g_r  = (const float*)d_in[9];
  P.b_r  = (const float*)d_in[10];
  P.Wo   = (const float*)d_in[11];
  P.bo   = (const float*)d_in[12];
  P.g_o  = (const float*)d_in[13];
  P.b_o  = (const float*)d_in[14];
  P.v0   = ws + off; off += 1638400;   // (N,8,T,V) -- shared by both paths
  P.s    = ws + off; off += 204800;    // (N,T,V)   -- shared
  P.pr   = ws + off; off += 16*NBC;
  P.patt = ws + off; off += 16*NBC;
  P.ph   = ws + off; off += 44*NBC;
  P.out  = (float*)d_out;
  // fallback-only buffers
  float* r0   = ws + off; off += 1638400;
  float* W2att= ws + off; off += 1638400;  // att
  float* hbuf = ws + off; off += 1638400;
  float* prF  = ws + off; off += 16*NBF;
  float* pattF= ws + off; off += 16*NBF;
  float* phF  = ws + off; off += 44*NBF;
  float* coef = ws + off; off += 32;
  float* hstat= ws + off; off += 44;
  float* fold = ws + off; off += 1024;
  float* bfold= ws + off; off += 128;

  void* args[] = { &P };
  hipError_t err = hipLaunchCooperativeKernel((const void*)mega, dim3(NBC), dim3(256),
                                              args, 0, stream);
  if (err != hipSuccess){
    // verified multi-kernel fallback
    k_proj  <<<NBF, 256, 0, stream>>>(P.x, P.Wv, P.bv, P.Wr, P.br, P.v0, r0, P.s, prF);
    k_att   <<<NBF, 256, 0, stream>>>(P.s, P.Ww, P.bw, P.v0, W2att, pattF);
    k_bncoef<<<16, 256, 0, stream>>>(prF, pattF, P.g_bn, P.b_bn, P.g_r, P.b_r, coef);
    k_h     <<<NBF, 256, 0, stream>>>(W2att, r0, coef, hbuf, phF);
    k_hred  <<<44, 256, 0, stream>>>(phF, hstat);
    k_fold  <<<1, 128, 0, stream>>>(hstat, P.Wo, P.bo, P.g_o, P.b_o, fold, bfold);
    k_out   <<<NBF, 256, 0, stream>>>(hbuf, fold, bfold, P.out);
  }
}

// Round 4
// 262.758 us; speedup vs baseline: 2.1762x; 2.1762x over previous
//
#include <hip/hip_runtime.h>
#include <math.h>

#define TV 3200          // T*V
#define NTV 204800       // N*T*V
#define NB 400           // blocks for 128-thread kernels (512 positions each)
constexpr float EPSF = 1e-5f;

// block = 128 threads (2 waves): shuffle -> lds -> per-block partial
template<int NS>
__device__ inline void partials2(const float (&vals)[NS], float* lds, float* out, int ncols){
  int lane = threadIdx.x & 63, wid = threadIdx.x >> 6;
  #pragma unroll
  for (int j = 0; j < NS; ++j){
    float v = vals[j];
    #pragma unroll
    for (int o = 32; o > 0; o >>= 1) v += __shfl_down(v, o);
    if (lane == 0) lds[j*2 + wid] = v;
  }
  __syncthreads();
  if ((int)threadIdx.x < NS)
    out[threadIdx.x*ncols + blockIdx.x] = lds[threadIdx.x*2] + lds[threadIdx.x*2 + 1];
}

// ---- K1: v0 = Wv@x+bv, r0 = Wr@x+br, s = mean_c x ; r0 stats. float4/thread ----
__global__ __launch_bounds__(128, 2) void k_proj(
    const float* __restrict__ x, const float* __restrict__ Wv, const float* __restrict__ bv,
    const float* __restrict__ Wr, const float* __restrict__ br,
    float* __restrict__ v0, float* __restrict__ r0, float* __restrict__ s,
    float* __restrict__ pr){
  __shared__ __align__(16) float sW[1024];   // transposed: [c*16 + j], j<8:Wv_r, j>=8:Wr_r
  __shared__ float lds[32];
  const int tid = threadIdx.x;
  for (int i = tid; i < 1024; i += 128){
    int c = i >> 4, j = i & 15;
    sW[i] = (j < 8) ? Wv[j*64 + c] : Wr[(j-8)*64 + c];
  }
  __syncthreads();
  const int p4 = (blockIdx.x*128 + tid) * 4;
  const int n = p4 / TV, tv4 = p4 - n*TV;
  const float* xb = x + (size_t)n*64*TV + tv4;
  float4 av[8], ar[8];
  #pragma unroll
  for (int r = 0; r < 8; ++r){
    av[r] = make_float4(0.f,0.f,0.f,0.f);
    ar[r] = make_float4(0.f,0.f,0.f,0.f);
  }
  float4 ss = make_float4(0.f,0.f,0.f,0.f);
  #pragma unroll 8
  for (int c = 0; c < 64; ++c){
    float4 xv = *(const float4*)(xb + (size_t)c*TV);
    ss.x += xv.x; ss.y += xv.y; ss.z += xv.z; ss.w += xv.w;
    #pragma unroll
    for (int r = 0; r < 8; ++r){
      float wv = sW[c*16 + r], wr = sW[c*16 + 8 + r];
      av[r].x = fmaf(wv, xv.x, av[r].x); av[r].y = fmaf(wv, xv.y, av[r].y);
      av[r].z = fmaf(wv, xv.z, av[r].z); av[r].w = fmaf(wv, xv.w, av[r].w);
      ar[r].x = fmaf(wr, xv.x, ar[r].x); ar[r].y = fmaf(wr, xv.y, ar[r].y);
      ar[r].z = fmaf(wr, xv.z, ar[r].z); ar[r].w = fmaf(wr, xv.w, ar[r].w);
    }
  }
  *(float4*)(s + p4) = make_float4(ss.x*0.015625f, ss.y*0.015625f, ss.z*0.015625f, ss.w*0.015625f);
  float vals[16];
  #pragma unroll
  for (int r = 0; r < 8; ++r){
    float bvr = bv[r], brr = br[r];
    float4 vv = make_float4(av[r].x+bvr, av[r].y+bvr, av[r].z+bvr, av[r].w+bvr);
    *(float4*)(v0 + (size_t)r*NTV + p4) = vv;
    float4 rr = make_float4(ar[r].x+brr, ar[r].y+brr, ar[r].z+brr, ar[r].w+brr);
    *(float4*)(r0 + (size_t)r*NTV + p4) = rr;
    vals[r]   = rr.x + rr.y + rr.z + rr.w;
    vals[8+r] = rr.x*rr.x + rr.y*rr.y + rr.z*rr.z + rr.w*rr.w;
  }
  partials2<16>(vals, lds, pr, NB);
}

// ---- K2: att = sum_u [sum_w tanh(Ww.m+bw)] * v0(t+u-2) ; att stats. LDS-staged ----
__global__ __launch_bounds__(128, 2) void k_att(
    const float* __restrict__ s, const float* __restrict__ Ww, const float* __restrict__ bw,
    const float* __restrict__ v0, float* __restrict__ att, float* __restrict__ patt){
  __shared__ __align__(16) float sS[616];        // s[P0-52 .. P0+564)
  __shared__ __align__(16) float sV[8*616];      // v0 channel tiles, same range
  __shared__ float sWw[128], sbw[32];
  __shared__ float lds[32];
  const int tid = threadIdx.x;
  if (tid < 125) sWw[tid] = Ww[tid];
  if (tid < 25)  sbw[tid] = bw[tid];
  const int P0 = blockIdx.x * 512;
  const int base = P0 - 52;
  for (int i = tid; i < 154; i += 128){
    int q = base + i*4;
    float4 val;
    if (q >= 0 && q + 3 < NTV) val = *(const float4*)(s + q);
    else {
      float tmp[4];
      #pragma unroll
      for (int j = 0; j < 4; ++j){ int qe = q + j; tmp[j] = (qe >= 0 && qe < NTV) ? s[qe] : 0.f; }
      val = make_float4(tmp[0], tmp[1], tmp[2], tmp[3]);
    }
    *(float4*)&sS[i*4] = val;
  }
  for (int i = tid; i < 1232; i += 128){
    int r = i / 154, j = i - r*154;
    int q = base + j*4;
    const float* vr = v0 + (size_t)r*NTV;
    float4 val;
    if (q >= 0 && q + 3 < NTV) val = *(const float4*)(vr + q);
    else {
      float tmp[4];
      #pragma unroll
      for (int jj = 0; jj < 4; ++jj){ int qe = q + jj; tmp[jj] = (qe >= 0 && qe < NTV) ? vr[qe] : 0.f; }
      val = make_float4(tmp[0], tmp[1], tmp[2], tmp[3]);
    }
    *(float4*)&sV[r*616 + j*4] = val;
  }
  __syncthreads();
  float vals[16];
  #pragma unroll
  for (int j = 0; j < 16; ++j) vals[j] = 0.f;
  #pragma unroll
  for (int e = 0; e < 4; ++e){
    const int p = P0 + e*128 + tid;          // lanes stride-1 -> conflict-free LDS
    const int n = p / TV, tv = p - n*TV;
    const int li0 = e*128 + tid + 52;
    float m[5];
    #pragma unroll
    for (int k = 0; k < 5; ++k){
      int q = tv + (k-2)*25;
      m[k] = (q >= 0 && q < TV) ? sS[li0 + (k-2)*25] : 0.f;
    }
    float acc[8] = {0.f,0.f,0.f,0.f,0.f,0.f,0.f,0.f};
    #pragma unroll
    for (int u = 0; u < 5; ++u){
      float w2u = 0.f;
      #pragma unroll
      for (int w = 0; w < 5; ++w){
        int o = w*5 + u;
        float z = sbw[o];
        #pragma unroll
        for (int k = 0; k < 5; ++k) z = fmaf(sWw[o*5+k], m[k], z);
        w2u += tanhf(z);
      }
      int q = tv + (u-2)*25;
      if (q >= 0 && q < TV){
        int li = li0 + (u-2)*25;
        #pragma unroll
        for (int r = 0; r < 8; ++r) acc[r] = fmaf(w2u, sV[r*616 + li], acc[r]);
      }
    }
    #pragma unroll
    for (int r = 0; r < 8; ++r){
      att[(size_t)r*NTV + p] = acc[r];
      vals[r] += acc[r]; vals[8+r] += acc[r]*acc[r];
    }
  }
  partials2<16>(vals, lds, patt, NB);
}

// ---- K3: BN coefs for att & res: coef[0..7]=a_att,[8..15]=c_att,[16..23]=a_r,[24..31]=c_r ----
__global__ __launch_bounds__(256) void k_bncoef(const float* __restrict__ pr,
    const float* __restrict__ patt,
    const float* __restrict__ g_bn, const float* __restrict__ b_bn,
    const float* __restrict__ g_r, const float* __restrict__ b_r,
    float* __restrict__ coef){
  __shared__ float lds[8];
  int b = blockIdx.x;                 // 0..15
  bool isatt = (b >= 8);
  int r = b & 7;
  const float* ps = (isatt ? patt : pr) + r*NB;
  const float* pq = (isatt ? patt : pr) + (8+r)*NB;
  float s1 = 0.f, s2 = 0.f;
  for (int i = threadIdx.x; i < NB; i += 256){ s1 += ps[i]; s2 += pq[i]; }
  int lane = threadIdx.x & 63, wid = threadIdx.x >> 6;
  #pragma unroll
  for (int o = 32; o > 0; o >>= 1){ s1 += __shfl_down(s1, o); s2 += __shfl_down(s2, o); }
  if (lane == 0){ lds[wid] = s1; lds[4+wid] = s2; }
  __syncthreads();
  if (threadIdx.x == 0){
    float sum = lds[0]+lds[1]+lds[2]+lds[3];
    float sq  = lds[4]+lds[5]+lds[6]+lds[7];
    float mu  = sum / (float)NTV;
    float var = sq / (float)NTV - mu*mu;
    float g  = isatt ? g_bn[r] : g_r[r];
    float bb = isatt ? b_bn[r] : b_r[r];
    float a = g * rsqrtf(var + EPSF);
    int b0 = isatt ? 0 : 16;
    coef[b0 + r] = a;
    coef[b0 + 8 + r] = bb - a*mu;
  }
}

// ---- K4: h = leaky(bn(att)+bn(r0)) ; 44 moment partials. float4/thread ----
__global__ __launch_bounds__(128, 2) void k_h(
    const float* __restrict__ att, const float* __restrict__ r0,
    const float* __restrict__ coef, float* __restrict__ h, float* __restrict__ ph){
  __shared__ float sc[32];
  __shared__ float lds[96];
  const int tid = threadIdx.x;
  if (tid < 32) sc[tid] = coef[tid];
  __syncthreads();
  const int p4 = (blockIdx.x*128 + tid) * 4;
  float4 hv[8];
  float vals[44];
  #pragma unroll
  for (int r = 0; r < 8; ++r){
    float4 a = *(const float4*)(att + (size_t)r*NTV + p4);
    float4 b = *(const float4*)(r0  + (size_t)r*NTV + p4);
    float ca = sc[r], cb = sc[8+r], cc = sc[16+r], cd = sc[24+r];
    float4 z;
    z.x = ca*a.x + cb + cc*b.x + cd;
    z.y = ca*a.y + cb + cc*b.y + cd;
    z.z = ca*a.z + cb + cc*b.z + cd;
    z.w = ca*a.w + cb + cc*b.w + cd;
    hv[r].x = (z.x >= 0.f) ? z.x : 0.1f*z.x;
    hv[r].y = (z.y >= 0.f) ? z.y : 0.1f*z.y;
    hv[r].z = (z.z >= 0.f) ? z.z : 0.1f*z.z;
    hv[r].w = (z.w >= 0.f) ? z.w : 0.1f*z.w;
    *(float4*)(h + (size_t)r*NTV + p4) = hv[r];
    vals[r] = hv[r].x + hv[r].y + hv[r].z + hv[r].w;
  }
  int cnt = 8;
  #pragma unroll
  for (int r = 0; r < 8; ++r)
    #pragma unroll
    for (int r2 = r; r2 < 8; ++r2){
      vals[cnt++] = hv[r].x*hv[r2].x + hv[r].y*hv[r2].y + hv[r].z*hv[r2].z + hv[r].w*hv[r2].w;
    }
  partials2<44>(vals, lds, ph, NB);
}

// ---- K5: reduce 44 h-stats + analytic BN fold into Wo', bo' ----
__global__ __launch_bounds__(256) void k_foldred(const float* __restrict__ ph,
    const float* __restrict__ Wo, const float* __restrict__ bo,
    const float* __restrict__ g_o, const float* __restrict__ b_o,
    float* __restrict__ fold, float* __restrict__ bfold){
  __shared__ float sm[176];
  __shared__ float s44[44];
  __shared__ double muh[8];
  __shared__ double exx[64];
  const int tid = threadIdx.x;
  if (tid < 176){
    int j = tid >> 2, q = tid & 3;
    const float* row = ph + j*NB + q*100;
    float acc = 0.f;
    for (int i = 0; i < 100; ++i) acc += row[i];
    sm[tid] = acc;
  }
  __syncthreads();
  if (tid < 44) s44[tid] = sm[4*tid] + sm[4*tid+1] + sm[4*tid+2] + sm[4*tid+3];
  __syncthreads();
  if (tid < 8) muh[tid] = (double)s44[tid] / (double)NTV;
  if (tid == 0){
    int cnt = 8;
    for (int r = 0; r < 8; ++r)
      for (int r2 = r; r2 < 8; ++r2){
        double e = (double)s44[cnt++] / (double)NTV;
        exx[r*8+r2] = e; exx[r2*8+r] = e;
      }
  }
  __syncthreads();
  if (tid < 128){
    double w[8];
    #pragma unroll
    for (int r = 0; r < 8; ++r) w[r] = (double)Wo[tid*8+r];
    double bob = (double)bo[tid];
    double mu = bob;
    for (int r = 0; r < 8; ++r) mu += w[r]*muh[r];
    double t2 = 0.0;
    for (int r = 0; r < 8; ++r)
      for (int r2 = 0; r2 < 8; ++r2) t2 += w[r]*w[r2]*exx[r*8+r2];
    double ey2 = t2 + 2.0*bob*(mu - bob) + bob*bob;
    double var = ey2 - mu*mu;
    double a = (double)g_o[tid] / sqrt(var + (double)EPSF);
    #pragma unroll
    for (int r = 0; r < 8; ++r) fold[tid*8+r] = (float)(a * w[r]);
    bfold[tid] = (float)(a * (bob - mu) + (double)b_o[tid]);
  }
}

// ---- K6: out = fold . h + bfold ; float4/thread, grid (200, 4) over o-groups ----
__global__ __launch_bounds__(256) void k_out(const float* __restrict__ h,
    const float* __restrict__ fold, const float* __restrict__ bfold,
    float* __restrict__ out){
  __shared__ float sW[256], sB[32];
  const int tid = threadIdx.x;
  const int yo = blockIdx.y * 32;
  sW[tid] = fold[yo*8 + tid];
  if (tid < 32) sB[tid] = bfold[yo + tid];
  __syncthreads();
  const int p4 = (blockIdx.x*256 + tid) * 4;
  const int n = p4 / TV, tv4 = p4 - n*TV;
  float4 hv[8];
  #pragma unroll
  for (int r = 0; r < 8; ++r) hv[r] = *(const float4*)(h + (size_t)r*NTV + p4);
  float* ob = out + (size_t)n*128*TV + tv4;
  #pragma unroll 4
  for (int o = 0; o < 32; ++o){
    float b = sB[o];
    float4 y = make_float4(b, b, b, b);
    #pragma unroll
    for (int r = 0; r < 8; ++r){
      float w = sW[o*8+r];
      y.x = fmaf(w, hv[r].x, y.x);
      y.y = fmaf(w, hv[r].y, y.y);
      y.z = fmaf(w, hv[r].z, y.z);
      y.w = fmaf(w, hv[r].w, y.w);
    }
    *(float4*)(ob + (size_t)(yo + o)*TV) = y;
  }
}

extern "C" void kernel_launch(void* const* d_in, const int* in_sizes, int n_in,
                              void* d_out, int out_size, void* d_ws, size_t ws_size,
                              hipStream_t stream){
  const float* x    = (const float*)d_in[0];
  const float* Wv   = (const float*)d_in[1];
  const float* bv   = (const float*)d_in[2];
  const float* Ww   = (const float*)d_in[3];
  const float* bw   = (const float*)d_in[4];
  const float* g_bn = (const float*)d_in[5];
  const float* b_bn = (const float*)d_in[6];
  const float* Wr   = (const float*)d_in[7];
  const float* br   = (const float*)d_in[8];
  const float* g_r  = (const float*)d_in[9];
  const float* b_r  = (const float*)d_in[10];
  const float* Wo   = (const float*)d_in[11];
  const float* bo   = (const float*)d_in[12];
  const float* g_o  = (const float*)d_in[13];
  const float* b_o  = (const float*)d_in[14];

  float* ws = (float*)d_ws;
  size_t off = 0;
  float* v0   = ws + off; off += 8*NTV;    // channel-major (r, n*T*V)
  float* r0   = ws + off; off += 8*NTV;
  float* s    = ws + off; off += NTV;
  float* att  = ws + off; off += 8*NTV;
  float* hbuf = ws + off; off += 8*NTV;
  float* pr   = ws + off; off += 16*NB;
  float* patt = ws + off; off += 16*NB;
  float* ph   = ws + off; off += 44*NB;
  float* coef = ws + off; off += 32;
  float* fold = ws + off; off += 1024;
  float* bfold= ws + off; off += 128;

  k_proj   <<<NB, 128, 0, stream>>>(x, Wv, bv, Wr, br, v0, r0, s, pr);
  k_att    <<<NB, 128, 0, stream>>>(s, Ww, bw, v0, att, patt);
  k_bncoef <<<16, 256, 0, stream>>>(pr, patt, g_bn, b_bn, g_r, b_r, coef);
  k_h      <<<NB, 128, 0, stream>>>(att, r0, coef, hbuf, ph);
  k_foldred<<<1, 256, 0, stream>>>(ph, Wo, bo, g_o, b_o, fold, bfold);
  k_out    <<<dim3(200, 4), 256, 0, stream>>>(hbuf, fold, bfold, (float*)d_out);
}

// Round 5
// 253.447 us; speedup vs baseline: 2.2561x; 1.0367x over previous
//
#include <hip/hip_runtime.h>
#include <math.h>

#define TV 3200          // T*V
#define NTV 204800       // N*T*V
#define NB 800           // blocks of 256 threads, 1 position/thread
constexpr float EPSF = 1e-5f;

// block = 256 threads (4 waves): shuffle -> lds -> per-block partial
template<int NS>
__device__ inline void partials(const float (&vals)[NS], float* lds, float* out, int ncols){
  int lane = threadIdx.x & 63, wid = threadIdx.x >> 6;
  #pragma unroll
  for (int j = 0; j < NS; ++j){
    float v = vals[j];
    #pragma unroll
    for (int o = 32; o > 0; o >>= 1) v += __shfl_down(v, o);
    if (lane == 0) lds[j*4 + wid] = v;
  }
  __syncthreads();
  if ((int)threadIdx.x < NS)
    out[threadIdx.x*ncols + blockIdx.x] =
      lds[threadIdx.x*4+0] + lds[threadIdx.x*4+1] + lds[threadIdx.x*4+2] + lds[threadIdx.x*4+3];
}

// ---- K1: v0 = Wv@x+bv, r0 = Wr@x+br, s = mean_c x ; r0 stats ----
__global__ __launch_bounds__(256, 4) void k_proj(
    const float* __restrict__ x, const float* __restrict__ Wv, const float* __restrict__ bv,
    const float* __restrict__ Wr, const float* __restrict__ br,
    float* __restrict__ v0, float* __restrict__ r0, float* __restrict__ s,
    float* __restrict__ pr){
  __shared__ __align__(16) float sW[1024];   // transposed: [c*16+j], j<8:Wv, j>=8:Wr
  __shared__ float lds[64];
  const int tid = threadIdx.x;
  for (int i = tid; i < 1024; i += 256){
    int c = i >> 4, j = i & 15;
    sW[i] = (j < 8) ? Wv[j*64 + c] : Wr[(j-8)*64 + c];
  }
  __syncthreads();
  const int p = blockIdx.x*256 + tid;
  const int n = p / TV, tv = p - n*TV;
  const float* xp = x + (size_t)n*64*TV + tv;
  float av[8] = {0,0,0,0,0,0,0,0};
  float ar[8] = {0,0,0,0,0,0,0,0};
  float ssum = 0.f;
  #pragma unroll 8
  for (int c = 0; c < 64; ++c){
    float xv = xp[(size_t)c*TV];
    ssum += xv;
    #pragma unroll
    for (int r = 0; r < 8; ++r){
      av[r] = fmaf(sW[c*16 + r],     xv, av[r]);
      ar[r] = fmaf(sW[c*16 + 8 + r], xv, ar[r]);
    }
  }
  s[p] = ssum * 0.015625f;
  float vals[16];
  #pragma unroll
  for (int r = 0; r < 8; ++r){
    v0[(size_t)r*NTV + p] = av[r] + bv[r];
    float rr = ar[r] + br[r];
    r0[(size_t)r*NTV + p] = rr;
    vals[r] = rr; vals[8+r] = rr*rr;
  }
  partials<16>(vals, lds, pr, NB);
}

// ---- K2: att = sum_u [sum_w tanh(Ww.m+bw)] * v0(t+u-2) ; att stats. LDS-staged halo ----
__global__ __launch_bounds__(256, 4) void k_att(
    const float* __restrict__ s, const float* __restrict__ Ww, const float* __restrict__ bw,
    const float* __restrict__ v0, float* __restrict__ att, float* __restrict__ patt){
  __shared__ float sS[360];                 // window [P0-52, P0+308)
  __shared__ float sV[8*360];
  __shared__ float sWw[128], sbw[32];
  __shared__ float lds[64];
  const int tid = threadIdx.x;
  if (tid < 125) sWw[tid] = Ww[tid];
  if (tid < 25)  sbw[tid] = bw[tid];
  const int P0 = blockIdx.x * 256;
  const int base = P0 - 52;
  for (int i = tid; i < 360; i += 256){
    int q = base + i;
    sS[i] = (q >= 0 && q < NTV) ? s[q] : 0.f;
  }
  #pragma unroll
  for (int r = 0; r < 8; ++r){
    const float* vr = v0 + (size_t)r*NTV;
    for (int i = tid; i < 360; i += 256){
      int q = base + i;
      sV[r*360 + i] = (q >= 0 && q < NTV) ? vr[q] : 0.f;
    }
  }
  __syncthreads();
  const int p = P0 + tid;
  const int n = p / TV, tv = p - n*TV;
  const int li = tid + 52;
  float m[5];
  #pragma unroll
  for (int k = 0; k < 5; ++k){
    int q = tv + (k-2)*25;
    m[k] = (q >= 0 && q < TV) ? sS[li + (k-2)*25] : 0.f;
  }
  float acc[8] = {0,0,0,0,0,0,0,0};
  #pragma unroll
  for (int u = 0; u < 5; ++u){
    float w2u = 0.f;
    #pragma unroll
    for (int w = 0; w < 5; ++w){
      int o = w*5 + u;
      float z = sbw[o];
      #pragma unroll
      for (int k = 0; k < 5; ++k) z = fmaf(sWw[o*5+k], m[k], z);
      w2u += tanhf(z);
    }
    int q = tv + (u-2)*25;
    if (q >= 0 && q < TV){
      int li2 = li + (u-2)*25;
      #pragma unroll
      for (int r = 0; r < 8; ++r) acc[r] = fmaf(w2u, sV[r*360 + li2], acc[r]);
    }
  }
  float vals[16];
  #pragma unroll
  for (int r = 0; r < 8; ++r){
    att[(size_t)r*NTV + p] = acc[r];
    vals[r] = acc[r]; vals[8+r] = acc[r]*acc[r];
  }
  partials<16>(vals, lds, patt, NB);
}

// ---- K3: BN coefs: coef[0..7]=a_att,[8..15]=c_att,[16..23]=a_r,[24..31]=c_r ----
__global__ __launch_bounds__(256) void k_bncoef(const float* __restrict__ pr,
    const float* __restrict__ patt,
    const float* __restrict__ g_bn, const float* __restrict__ b_bn,
    const float* __restrict__ g_r, const float* __restrict__ b_r,
    float* __restrict__ coef){
  __shared__ float lds[8];
  int b = blockIdx.x;                 // 0..15
  bool isatt = (b >= 8);
  int r = b & 7;
  const float* ps = (isatt ? patt : pr) + r*NB;
  const float* pq = (isatt ? patt : pr) + (8+r)*NB;
  float s1 = 0.f, s2 = 0.f;
  for (int i = threadIdx.x; i < NB; i += 256){ s1 += ps[i]; s2 += pq[i]; }
  int lane = threadIdx.x & 63, wid = threadIdx.x >> 6;
  #pragma unroll
  for (int o = 32; o > 0; o >>= 1){ s1 += __shfl_down(s1, o); s2 += __shfl_down(s2, o); }
  if (lane == 0){ lds[wid] = s1; lds[4+wid] = s2; }
  __syncthreads();
  if (threadIdx.x == 0){
    float sum = lds[0]+lds[1]+lds[2]+lds[3];
    float sq  = lds[4]+lds[5]+lds[6]+lds[7];
    float mu  = sum / (float)NTV;
    float var = sq / (float)NTV - mu*mu;
    float g  = isatt ? g_bn[r] : g_r[r];
    float bb = isatt ? b_bn[r] : b_r[r];
    float a = g * rsqrtf(var + EPSF);
    int b0 = isatt ? 0 : 16;
    coef[b0 + r] = a;
    coef[b0 + 8 + r] = bb - a*mu;
  }
}

// ---- K4: h = leaky(bn(att)+bn(r0)) ; 44 moment partials ----
__global__ __launch_bounds__(256, 4) void k_h(
    const float* __restrict__ att, const float* __restrict__ r0,
    const float* __restrict__ coef, float* __restrict__ h, float* __restrict__ ph){
  __shared__ float sc[32];
  __shared__ float lds[176];
  const int tid = threadIdx.x;
  if (tid < 32) sc[tid] = coef[tid];
  __syncthreads();
  const int p = blockIdx.x*256 + tid;
  float hv[8];
  float vals[44];
  #pragma unroll
  for (int r = 0; r < 8; ++r){
    float a = att[(size_t)r*NTV + p];
    float b = r0 [(size_t)r*NTV + p];
    float z = sc[r]*a + sc[8+r] + sc[16+r]*b + sc[24+r];
    hv[r] = (z >= 0.f) ? z : 0.1f*z;
    h[(size_t)r*NTV + p] = hv[r];
    vals[r] = hv[r];
  }
  int cnt = 8;
  #pragma unroll
  for (int r = 0; r < 8; ++r)
    #pragma unroll
    for (int r2 = r; r2 < 8; ++r2) vals[cnt++] = hv[r]*hv[r2];
  partials<44>(vals, lds, ph, NB);
}

// ---- K5: reduce 44 h-stats + analytic BN fold into Wo', bo' ----
__global__ __launch_bounds__(256) void k_foldred(const float* __restrict__ ph,
    const float* __restrict__ Wo, const float* __restrict__ bo,
    const float* __restrict__ g_o, const float* __restrict__ b_o,
    float* __restrict__ fold, float* __restrict__ bfold){
  __shared__ float sm[176];
  __shared__ float s44[44];
  __shared__ double muh[8];
  __shared__ double exx[64];
  const int tid = threadIdx.x;
  if (tid < 176){
    int j = tid >> 2, q = tid & 3;
    const float* row = ph + j*NB + q*200;
    float acc = 0.f;
    for (int i = 0; i < 200; ++i) acc += row[i];
    sm[tid] = acc;
  }
  __syncthreads();
  if (tid < 44) s44[tid] = sm[4*tid] + sm[4*tid+1] + sm[4*tid+2] + sm[4*tid+3];
  __syncthreads();
  if (tid < 8) muh[tid] = (double)s44[tid] / (double)NTV;
  if (tid == 0){
    int cnt = 8;
    for (int r = 0; r < 8; ++r)
      for (int r2 = r; r2 < 8; ++r2){
        double e = (double)s44[cnt++] / (double)NTV;
        exx[r*8+r2] = e; exx[r2*8+r] = e;
      }
  }
  __syncthreads();
  if (tid < 128){
    double w[8];
    #pragma unroll
    for (int r = 0; r < 8; ++r) w[r] = (double)Wo[tid*8+r];
    double bob = (double)bo[tid];
    double mu = bob;
    for (int r = 0; r < 8; ++r) mu += w[r]*muh[r];
    double t2 = 0.0;
    for (int r = 0; r < 8; ++r)
      for (int r2 = 0; r2 < 8; ++r2) t2 += w[r]*w[r2]*exx[r*8+r2];
    double ey2 = t2 + 2.0*bob*(mu - bob) + bob*bob;
    double var = ey2 - mu*mu;
    double a = (double)g_o[tid] / sqrt(var + (double)EPSF);
    #pragma unroll
    for (int r = 0; r < 8; ++r) fold[tid*8+r] = (float)(a * w[r]);
    bfold[tid] = (float)(a * (bob - mu) + (double)b_o[tid]);
  }
}

// ---- K6: out = fold . h + bfold ; float4/thread, grid (200,4) over o-groups ----
__global__ __launch_bounds__(256) void k_out(const float* __restrict__ h,
    const float* __restrict__ fold, const float* __restrict__ bfold,
    float* __restrict__ out){
  __shared__ float sW[256], sB[32];
  const int tid = threadIdx.x;
  const int yo = blockIdx.y * 32;
  sW[tid] = fold[yo*8 + tid];
  if (tid < 32) sB[tid] = bfold[yo + tid];
  __syncthreads();
  const int p4 = (blockIdx.x*256 + tid) * 4;
  const int n = p4 / TV, tv4 = p4 - n*TV;
  float4 hv[8];
  #pragma unroll
  for (int r = 0; r < 8; ++r) hv[r] = *(const float4*)(h + (size_t)r*NTV + p4);
  float* ob = out + (size_t)n*128*TV + tv4;
  #pragma unroll 4
  for (int o = 0; o < 32; ++o){
    float b = sB[o];
    float4 y = make_float4(b, b, b, b);
    #pragma unroll
    for (int r = 0; r < 8; ++r){
      float w = sW[o*8+r];
      y.x = fmaf(w, hv[r].x, y.x);
      y.y = fmaf(w, hv[r].y, y.y);
      y.z = fmaf(w, hv[r].z, y.z);
      y.w = fmaf(w, hv[r].w, y.w);
    }
    *(float4*)(ob + (size_t)(yo + o)*TV) = y;
  }
}

extern "C" void kernel_launch(void* const* d_in, const int* in_sizes, int n_in,
                              void* d_out, int out_size, void* d_ws, size_t ws_size,
                              hipStream_t stream){
  const float* x    = (const float*)d_in[0];
  const float* Wv   = (const float*)d_in[1];
  const float* bv   = (const float*)d_in[2];
  const float* Ww   = (const float*)d_in[3];
  const float* bw   = (const float*)d_in[4];
  const float* g_bn = (const float*)d_in[5];
  const float* b_bn = (const float*)d_in[6];
  const float* Wr   = (const float*)d_in[7];
  const float* br   = (const float*)d_in[8];
  const float* g_r  = (const float*)d_in[9];
  const float* b_r  = (const float*)d_in[10];
  const float* Wo   = (const float*)d_in[11];
  const float* bo   = (const float*)d_in[12];
  const float* g_o  = (const float*)d_in[13];
  const float* b_o  = (const float*)d_in[14];

  float* ws = (float*)d_ws;
  size_t off = 0;
  float* v0   = ws + off; off += 8*NTV;    // channel-major (r, n*T*V)
  float* r0   = ws + off; off += 8*NTV;
  float* s    = ws + off; off += NTV;
  float* att  = ws + off; off += 8*NTV;
  float* hbuf = ws + off; off += 8*NTV;
  float* pr   = ws + off; off += 16*NB;
  float* patt = ws + off; off += 16*NB;
  float* ph   = ws + off; off += 44*NB;
  float* coef = ws + off; off += 32;
  float* fold = ws + off; off += 1024;
  float* bfold= ws + off; off += 128;

  k_proj   <<<NB, 256, 0, stream>>>(x, Wv, bv, Wr, br, v0, r0, s, pr);
  k_att    <<<NB, 256, 0, stream>>>(s, Ww, bw, v0, att, patt);
  k_bncoef <<<16, 256, 0, stream>>>(pr, patt, g_bn, b_bn, g_r, b_r, coef);
  k_h      <<<NB, 256, 0, stream>>>(att, r0, coef, hbuf, ph);
  k_foldred<<<1, 256, 0, stream>>>(ph, Wo, bo, g_o, b_o, fold, bfold);
  k_out    <<<dim3(200, 4), 256, 0, stream>>>(hbuf, fold, bfold, (float*)d_out);
}